// Round 1
// baseline (106.334 us; speedup 1.0000x reference)
//
#include <hip/hip_runtime.h>
#include <hip/hip_bf16.h>

#define EPS 0.3f

__global__ void eps_clamp_kernel(const float4* __restrict__ in,
                                 float4* __restrict__ out,
                                 int n4) {
    int idx = blockIdx.x * blockDim.x + threadIdx.x;
    int stride = gridDim.x * blockDim.x;
    for (int i = idx; i < n4; i += stride) {
        float4 v = in[i];
        float4 r;
        {
            float x = v.x;
            r.x = (fabsf(x) < EPS) ? ((x < 0.0f) ? -EPS : EPS) : x;
        }
        {
            float x = v.y;
            r.y = (fabsf(x) < EPS) ? ((x < 0.0f) ? -EPS : EPS) : x;
        }
        {
            float x = v.z;
            r.z = (fabsf(x) < EPS) ? ((x < 0.0f) ? -EPS : EPS) : x;
        }
        {
            float x = v.w;
            r.w = (fabsf(x) < EPS) ? ((x < 0.0f) ? -EPS : EPS) : x;
        }
        out[i] = r;
    }
}

extern "C" void kernel_launch(void* const* d_in, const int* in_sizes, int n_in,
                              void* d_out, int out_size, void* d_ws, size_t ws_size,
                              hipStream_t stream) {
    const float* x = (const float*)d_in[0];
    float* out = (float*)d_out;
    int n = in_sizes[0];          // 8192*8192 = 67108864, divisible by 4
    int n4 = n / 4;

    const int block = 256;
    int grid = (n4 + block - 1) / block;
    if (grid > 2048) grid = 2048;  // grid-stride the rest (256 CU × 8 blocks)

    eps_clamp_kernel<<<grid, block, 0, stream>>>(
        (const float4*)x, (float4*)out, n4);
}